// Round 5
// baseline (281.213 us; speedup 1.0000x reference)
//
#include <hip/hip_runtime.h>

#define E_CNT 2000000
#define N_CNT 200000
#define B_CNT 100
#define R_CNT 13
#define G_CNT 512
#define T_CNT 10
#define OE_CNT 4

// Native vector type for nontemporal builtins (HIP_vector_type is rejected).
typedef float nfloat4 __attribute__((ext_vector_type(4)));

// Two packed tables: Ph[b][g][16] (r=0..12 used, 64B row = exactly 1 cache line),
// Po likewise. 3.28 MB each.
#define P_ROW 16
#define P_ONE ((size_t)B_CNT * G_CNT * P_ROW)
#define P_BYTES_TOTAL (2 * P_ONE * 4)

#define EDGES_PER_BLOCK 64
#define EDGE_BLOCKS (E_CNT / EDGES_PER_BLOCK)       // 31250, exact
#define NODE_BLOCKS ((N_CNT + 255) / 256)           // 782
#define OUT_OVL_OFF ((size_t)E_CNT * R_CNT)
#define OUT_NODE_OFF ((size_t)2 * E_CNT * R_CNT)

#define SH_STRIDE 32   // [edge][hop 0..12 | pad | ovl 16..28 | pad], 128B per edge

__global__ __launch_bounds__(256) void repack2_kernel(
    const float* __restrict__ hopping,
    const float* __restrict__ overlap,
    float* __restrict__ Ph,
    float* __restrict__ Po)
{
    int tid = blockIdx.x * 256 + threadIdx.x;       // 2600 blocks, exact
    int g = tid & (G_CNT - 1);
    int br = tid >> 9;                              // b*13 + r
    int r = br % R_CNT;
    int b = br / R_CNT;
    size_t src = (size_t)tid;                       // b*13*512 + r*512 + g
    size_t dst = ((size_t)(b * G_CNT + g)) * P_ROW + r;
    Ph[dst] = hopping[src];
    Po[dst] = overlap[src];
}

__global__ __launch_bounds__(256) void dftbsk_fused(
    const float* __restrict__ rij,
    const int*   __restrict__ edge_type,
    const float* __restrict__ Ph,
    const float* __restrict__ Po,
    const int*   __restrict__ atom_type,
    const float* __restrict__ onsite,
    float* __restrict__ out)
{
    if (blockIdx.x < EDGE_BLOCKS) {
        __shared__ float sh[EDGES_PER_BLOCK * SH_STRIDE];   // 8 KB

        int tid = threadIdx.x;
        int eL = tid >> 2;            // 0..63
        int j  = tid & 3;             // 0..3
        int e  = blockIdx.x * EDGES_PER_BLOCK + eL;

        // Stream reads, no reuse: non-temporal, don't pollute L2 (we need L2
        // for the gather tables).
        float r = __builtin_nontemporal_load(rij + e);
        int   b = __builtin_nontemporal_load(edge_type + e);

        // xx = linspace(1,6,512): closed-form interval + fraction.
        const float inv_dx = 511.0f / 5.0f;
        float s = (r - 1.0f) * inv_dx;
        int idx = (int)s;
        idx = max(0, min(G_CNT - 2, idx));
        float t = s - (float)idx;
        float omt = 1.0f - t;

        size_t base = ((size_t)((b << 9) + idx)) * P_ROW + 4 * j;
        float4 h0 = *(const float4*)(Ph + base);
        float4 h1 = *(const float4*)(Ph + base + P_ROW);
        float4 o0 = *(const float4*)(Po + base);
        float4 o1 = *(const float4*)(Po + base + P_ROW);

        float4 v, w;
        v.x = h0.x * omt + h1.x * t;  v.y = h0.y * omt + h1.y * t;
        v.z = h0.z * omt + h1.z * t;  v.w = h0.w * omt + h1.w * t;
        w.x = o0.x * omt + o1.x * t;  w.y = o0.y * omt + o1.y * t;
        w.z = o0.z * omt + o1.z * t;  w.w = o0.w * omt + o1.w * t;

        // Two b128 LDS writes; j==3 spills into the pads (13..15 / 29..31) - safe.
        *(float4*)(sh + eL * SH_STRIDE + 4 * j) = v;
        *(float4*)(sh + eL * SH_STRIDE + 16 + 4 * j) = w;
        __syncthreads();

        // Coalesced write-out: 2 tables x 832 floats = 416 float4 stores.
        size_t outBase = (size_t)blockIdx.x * (EDGES_PER_BLOCK * R_CNT);
        #pragma unroll
        for (int L = 0; L < 2; ++L) {
            int i4 = tid + L * 256;
            if (i4 < 416) {
                bool isOvl = i4 >= 208;
                unsigned f0 = (unsigned)(isOvl ? (i4 - 208) : i4) * 4u;
                nfloat4 q;
                #pragma unroll
                for (int k = 0; k < 4; ++k) {
                    unsigned f = f0 + k;
                    unsigned ee = f / 13u;
                    unsigned rr = f - ee * 13u;
                    q[k] = sh[ee * SH_STRIDE + (isOvl ? 16 : 0) + rr];
                }
                float* dst = out + (isOvl ? OUT_OVL_OFF : 0) + outBase + f0;
                // Write-once output: non-temporal, bypass L2/L3 allocation.
                __builtin_nontemporal_store(q, (nfloat4*)dst);
            }
        }
    } else {
        int n = (blockIdx.x - EDGE_BLOCKS) * 256 + threadIdx.x;
        if (n < N_CNT) {
            int t = atom_type[n];
            nfloat4 v;
            v[0] = onsite[t * OE_CNT + 0];
            v[1] = onsite[t * OE_CNT + 1];
            v[2] = onsite[t * OE_CNT + 2];
            v[3] = onsite[t * OE_CNT + 3];
            __builtin_nontemporal_store(v, (nfloat4*)(out + OUT_NODE_OFF + (size_t)n * OE_CNT));
        }
    }
}

// Fallback (round-1 style) if workspace is too small for the packed tables.
__global__ __launch_bounds__(256) void dftbsk_fallback(
    const float* __restrict__ rij,
    const int*   __restrict__ edge_type,
    const int*   __restrict__ atom_type,
    const float* __restrict__ xx,
    const float* __restrict__ hopping,
    const float* __restrict__ overlap,
    const float* __restrict__ onsite,
    float*       __restrict__ out)
{
    __shared__ float sxx[G_CNT];
    for (int i = threadIdx.x; i < G_CNT; i += blockDim.x) sxx[i] = xx[i];
    __syncthreads();

    long long gid = (long long)blockIdx.x * blockDim.x + threadIdx.x;
    if (gid < E_CNT) {
        int e = (int)gid;
        float r = rij[e];
        int b = edge_type[e];
        const float inv_dx = (float)(G_CNT - 1) / 5.0f;
        int idx = (int)floorf((r - 1.0f) * inv_dx);
        idx = max(0, min(G_CNT - 2, idx));
        while (idx > 0 && r < sxx[idx]) --idx;
        while (idx < G_CNT - 2 && r >= sxx[idx + 1]) ++idx;
        float x0 = sxx[idx], x1 = sxx[idx + 1];
        float t = (r - x0) / (x1 - x0);
        float omt = 1.0f - t;
        const float* hb = hopping + (size_t)b * (R_CNT * G_CNT) + idx;
        const float* ob = overlap + (size_t)b * (R_CNT * G_CNT) + idx;
        float* outh = out + (size_t)e * R_CNT;
        float* outo = out + OUT_OVL_OFF + (size_t)e * R_CNT;
        #pragma unroll
        for (int rr = 0; rr < R_CNT; ++rr)
            outh[rr] = hb[rr * G_CNT] * omt + hb[rr * G_CNT + 1] * t;
        #pragma unroll
        for (int rr = 0; rr < R_CNT; ++rr)
            outo[rr] = ob[rr * G_CNT] * omt + ob[rr * G_CNT + 1] * t;
    } else if (gid < (long long)E_CNT + N_CNT) {
        int n = (int)(gid - E_CNT);
        int t = atom_type[n];
        float4 v;
        v.x = onsite[t * OE_CNT + 0];
        v.y = onsite[t * OE_CNT + 1];
        v.z = onsite[t * OE_CNT + 2];
        v.w = onsite[t * OE_CNT + 3];
        *(float4*)(out + OUT_NODE_OFF + (size_t)n * OE_CNT) = v;
    }
}

extern "C" void kernel_launch(void* const* d_in, const int* in_sizes, int n_in,
                              void* d_out, int out_size, void* d_ws, size_t ws_size,
                              hipStream_t stream) {
    const float* rij        = (const float*)d_in[0];
    const int*   edge_type  = (const int*)d_in[1];
    const int*   atom_type  = (const int*)d_in[2];
    const float* xx         = (const float*)d_in[3];
    const float* hopping    = (const float*)d_in[4];
    const float* overlap    = (const float*)d_in[5];
    const float* onsite     = (const float*)d_in[6];
    float* out = (float*)d_out;

    if (ws_size >= P_BYTES_TOTAL) {
        float* Ph = (float*)d_ws;
        float* Po = Ph + P_ONE;
        const int repack_total = B_CNT * R_CNT * G_CNT;   // 665600 = 2600*256
        repack2_kernel<<<repack_total / 256, 256, 0, stream>>>(hopping, overlap, Ph, Po);
        dftbsk_fused<<<EDGE_BLOCKS + NODE_BLOCKS, 256, 0, stream>>>(
            rij, edge_type, Ph, Po, atom_type, onsite, out);
    } else {
        const long long total = (long long)E_CNT + N_CNT;
        const int grid = (int)((total + 255) / 256);
        dftbsk_fallback<<<grid, 256, 0, stream>>>(rij, edge_type, atom_type, xx,
                                                  hopping, overlap, onsite, out);
    }
}